// Round 8
// baseline (49.092 us; speedup 1.0000x reference)
//
#include <hip/hip_runtime.h>
#include <math.h>

// ---- problem constants ----
#define NB    512   // batch
#define STATE 512
#define IMS   224
#define TSB   768   // 3*16*16
#define HGN   128
#define GN    256
#define WPITCH 65   // 64 + 1 pad
#define MAGIC 0x00C0FFEEu

// ---- aliased LDS layout (49152 B total) ----
// stage A: [0, 33280)  win[2][64*WPITCH]
// stage B: [0, 12288)  gls[4][768]
//          [12288, 45056) part4[16][4][128]
//          [0, 32768)  part6[8][4][256]   (gls/part4 dead by then)
//          [45056, 47104) s_hg[4][128]
//          [47104, 49152) s_hl[4][128]
#define SM_TOTAL 49152

// depth-1 (32->16) antialiased linear weights: taps at j = 2*o-1 + a
__device__ __forceinline__ void d1w(int o, float w[4]) {
    w[0] = 0.125f; w[1] = 0.375f; w[2] = 0.375f; w[3] = 0.125f;
    if (o == 0)  { w[0] = 0.f;      w[1] = 3.f/7.f; w[2] = 3.f/7.f; w[3] = 1.f/7.f; }
    if (o == 15) { w[0] = 1.f/7.f;  w[1] = 3.f/7.f; w[2] = 3.f/7.f; w[3] = 0.f; }
}
// depth-2 (64->16) weights: taps at j = 4*o-2 + a
__device__ __forceinline__ void d2w(int o, float w[8]) {
    const float s = 1.f/32.f;
    w[0]=1*s; w[1]=3*s; w[2]=5*s; w[3]=7*s; w[4]=7*s; w[5]=5*s; w[6]=3*s; w[7]=1*s;
    if (o == 0)  { const float t=1.f/28.f; w[0]=0.f; w[1]=0.f; w[2]=5*t; w[3]=7*t; w[4]=7*t; w[5]=5*t; w[6]=3*t; w[7]=1*t; }
    if (o == 15) { const float t=1.f/28.f; w[0]=1*t; w[1]=3*t; w[2]=5*t; w[3]=7*t; w[4]=7*t; w[5]=5*t; w[6]=0.f; w[7]=0.f; }
}

#define FMA4(acc, sc, w4) \
    acc.x += (sc) * (w4).x; acc.y += (sc) * (w4).y; \
    acc.z += (sc) * (w4).z; acc.w += (sc) * (w4).w;

// One launch, two logical grids:
//   stage A (all 256 blocks, 2 samples each): loc + window + glimpses -> gl_g
//   stage B (even blocks only, 4 samples each): hg/hl/g GEMVs (weight L2
//   traffic halved vs SPB=2). Pairwise flag sync, device-scope per G16.
__global__ __launch_bounds__(512) void fused_pair(
    const float* __restrict__ out_state,  // [512][512]
    const float* __restrict__ img,        // [512][224][224]
    const float* __restrict__ W_loc, const float* __restrict__ b_loc,
    const float* __restrict__ W_hg,  const float* __restrict__ b_hg,
    const float* __restrict__ W_hl,  const float* __restrict__ b_hl,
    const float* __restrict__ W_gs,  const float* __restrict__ b_gs,
    const float* __restrict__ W_ls,  const float* __restrict__ b_ls,
    float* __restrict__ gl_g,             // ws [512][768]
    float* __restrict__ loc_g,            // ws [512][2]
    unsigned int* __restrict__ flags,     // ws [128]
    float* __restrict__ out)              // [512][256]
{
    __shared__ __align__(16) char smem[SM_TOTAL];
    __shared__ float red[8][2];
    __shared__ int   s_li[2][2];

    const int t  = threadIdx.x;
    const int b0 = blockIdx.x * 2;

    // ================= stage A: loc + windows + glimpses =================
    float* win = (float*)smem;   // [2][64*WPITCH]

    // phase 1: loc = clip(output @ W_loc + b_loc)
    {
        int s = t >> 8, k = t & 255;
        const float* orow = out_state + (size_t)(b0 + s) * STATE;
        float x0 = orow[k], x1 = orow[k + 256];
        float a0 = x0 * W_loc[k*2]     + x1 * W_loc[(k+256)*2];
        float a1 = x0 * W_loc[k*2 + 1] + x1 * W_loc[(k+256)*2 + 1];
        for (int off = 32; off; off >>= 1) {
            a0 += __shfl_down(a0, off);
            a1 += __shfl_down(a1, off);
        }
        if ((t & 63) == 0) { red[t>>6][0] = a0; red[t>>6][1] = a1; }
    }
    __syncthreads();
    if ((t & 255) == 0) {
        int s = t >> 8;
        float l0 = red[4*s][0]+red[4*s+1][0]+red[4*s+2][0]+red[4*s+3][0] + b_loc[0];
        float l1 = red[4*s][1]+red[4*s+1][1]+red[4*s+2][1]+red[4*s+3][1] + b_loc[1];
        l0 = fminf(fmaxf(l0, -1.f), 1.f);
        l1 = fminf(fmaxf(l1, -1.f), 1.f);
        s_li[s][0] = (int)rintf((l0 + 1.f) * 0.5f * (float)IMS);
        s_li[s][1] = (int)rintf((l1 + 1.f) * 0.5f * (float)IMS);
        loc_g[(b0 + s)*2 + 0] = l0;
        loc_g[(b0 + s)*2 + 1] = l1;
    }
    __syncthreads();

    // phase 2: 64x64 windows centered at loc, zero outside image
    #pragma unroll
    for (int i = 0; i < 16; ++i) {
        int idx = t + i * 512;
        int s = idx >> 12, rem = idx & 4095;
        int r = rem >> 6, c = rem & 63;
        int rr = s_li[s][0] - 32 + r, cc = s_li[s][1] - 32 + c;
        float v = 0.f;
        if ((unsigned)rr < (unsigned)IMS && (unsigned)cc < (unsigned)IMS)
            v = img[(size_t)(b0 + s) * IMS * IMS + rr * IMS + cc];
        win[s * (64*WPITCH) + r * WPITCH + c] = v;
    }
    __syncthreads();

    // phase 3: 3-depth glimpses -> gl_g (coalesced per 256-thread group)
    {
        int s = t >> 8, p = t & 255, r = p >> 4, c = p & 15;
        const float* w = win + s * (64*WPITCH);
        float* glb = gl_g + (size_t)(b0 + s) * TSB;
        glb[p] = w[(24 + r) * WPITCH + (24 + c)];
        {
            float wr[4], wc[4];
            d1w(r, wr); d1w(c, wc);
            int jr0 = 16 + 2*r - 1, jc0 = 16 + 2*c - 1;
            float acc = 0.f;
            #pragma unroll
            for (int a = 0; a < 4; ++a) {
                float rowsum = 0.f;
                #pragma unroll
                for (int bb = 0; bb < 4; ++bb)
                    rowsum += wc[bb] * w[(jr0 + a) * WPITCH + (jc0 + bb)];
                acc += wr[a] * rowsum;
            }
            glb[256 + p] = acc;
        }
        {
            float wr[8], wc[8];
            d2w(r, wr); d2w(c, wc);
            int jr0 = 4*r - 2, jc0 = 4*c - 2;
            float acc = 0.f;
            #pragma unroll
            for (int a = 0; a < 8; ++a) {
                int jr = min(max(jr0 + a, 0), 63);
                float rowsum = 0.f;
                #pragma unroll
                for (int bb = 0; bb < 8; ++bb) {
                    int jc = min(max(jc0 + bb, 0), 63);
                    rowsum += wc[bb] * w[jr * WPITCH + jc];
                }
                acc += wr[a] * rowsum;
            }
            glb[512 + p] = acc;
        }
    }
    __syncthreads();

    // ================= pairwise handoff =================
    const int pair = blockIdx.x >> 1;
    if (blockIdx.x & 1) {
        // producer-only block: publish and exit
        __threadfence();
        if (t == 0)
            __hip_atomic_store(&flags[pair], MAGIC, __ATOMIC_RELEASE,
                               __HIP_MEMORY_SCOPE_AGENT);
        return;
    }
    // consumer: wait for partner (bounded spin as safety valve)
    if (t == 0) {
        for (long it = 0; it < (1L << 26); ++it) {
            if (__hip_atomic_load(&flags[pair], __ATOMIC_ACQUIRE,
                                  __HIP_MEMORY_SCOPE_AGENT) == MAGIC) break;
        }
    }
    __syncthreads();
    __threadfence();   // make partner's gl/loc visible to all threads

    // ================= stage B: GEMVs at 4 samples/block =================
    float* gls   = (float*)smem;             // [4][768]
    float* part4 = (float*)(smem + 12288);   // [16][4][128]
    float* part6 = (float*)smem;             // [8][4][256]
    float* s_hg  = (float*)(smem + 45056);   // [4][128]
    float* s_hl  = (float*)(smem + 47104);   // [4][128]
    const int b4 = b0;                       // samples b4 .. b4+3

    // B0: stage 4 gl rows (768 float4)
    {
        const float4* src = (const float4*)(gl_g + (size_t)b4 * TSB);
        float4* dst = (float4*)gls;
        dst[t] = src[t];
        if (t < 256) dst[512 + t] = src[512 + t];
    }
    __syncthreads();

    // B1: hg partials. cg = t&31 (4 cols of 128), q = t>>5 (16 k-groups of 48)
    {
        int cg = t & 31, q = t >> 5;
        const float* g0 = gls + 0*TSB + q * 48;
        const float* g1 = gls + 1*TSB + q * 48;
        const float* g2 = gls + 2*TSB + q * 48;
        const float* g3 = gls + 3*TSB + q * 48;
        const float* wp = W_hg + (size_t)(q * 48) * HGN + cg * 4;
        float4 acc0 = make_float4(0.f,0.f,0.f,0.f);
        float4 acc1 = acc0, acc2 = acc0, acc3 = acc0;
        #pragma unroll 8
        for (int k = 0; k < 48; ++k) {
            float4 w4 = *(const float4*)(wp + (size_t)k * HGN);
            FMA4(acc0, g0[k], w4);
            FMA4(acc1, g1[k], w4);
            FMA4(acc2, g2[k], w4);
            FMA4(acc3, g3[k], w4);
        }
        *(float4*)&part4[(q*4 + 0)*HGN + cg*4] = acc0;
        *(float4*)&part4[(q*4 + 1)*HGN + cg*4] = acc1;
        *(float4*)&part4[(q*4 + 2)*HGN + cg*4] = acc2;
        *(float4*)&part4[(q*4 + 3)*HGN + cg*4] = acc3;
    }
    __syncthreads();

    // B2: reduce hg partials + hl (one (s,col) per thread)
    {
        int s = t >> 7, col = t & 127;
        float a = b_hg[col];
        #pragma unroll
        for (int q = 0; q < 16; ++q) a += part4[(q*4 + s)*HGN + col];
        s_hg[s*HGN + col] = fmaxf(a, 0.f);
        float l0 = loc_g[(b4 + s)*2], l1 = loc_g[(b4 + s)*2 + 1];
        s_hl[s*HGN + col] = fmaxf(l0 * W_hl[col] + l1 * W_hl[HGN + col] + b_hl[col], 0.f);
    }
    __syncthreads();

    // B3: g partials. cg = t&63 (4 cols of 256), q = t>>6 (8 j-groups of 16)
    {
        int cg = t & 63, q = t >> 6;
        const float* wgs = W_gs + (size_t)(q * 16) * GN + cg * 4;
        const float* wls = W_ls + (size_t)(q * 16) * GN + cg * 4;
        float4 acc0 = make_float4(0.f,0.f,0.f,0.f);
        float4 acc1 = acc0, acc2 = acc0, acc3 = acc0;
        #pragma unroll 4
        for (int j = 0; j < 16; ++j) {
            float4 a4 = *(const float4*)(wgs + (size_t)j * GN);
            float4 b4v = *(const float4*)(wls + (size_t)j * GN);
            int jj = q * 16 + j;
            FMA4(acc0, s_hg[0*HGN + jj], a4); FMA4(acc0, s_hl[0*HGN + jj], b4v);
            FMA4(acc1, s_hg[1*HGN + jj], a4); FMA4(acc1, s_hl[1*HGN + jj], b4v);
            FMA4(acc2, s_hg[2*HGN + jj], a4); FMA4(acc2, s_hl[2*HGN + jj], b4v);
            FMA4(acc3, s_hg[3*HGN + jj], a4); FMA4(acc3, s_hl[3*HGN + jj], b4v);
        }
        *(float4*)&part6[(q*4 + 0)*GN + cg*4] = acc0;
        *(float4*)&part6[(q*4 + 1)*GN + cg*4] = acc1;
        *(float4*)&part6[(q*4 + 2)*GN + cg*4] = acc2;
        *(float4*)&part6[(q*4 + 3)*GN + cg*4] = acc3;
    }
    __syncthreads();

    // B4: final reduce, 1024 outputs, 2 per thread
    {
        int n = t & 255, s0 = t >> 8;
        #pragma unroll
        for (int sl = 0; sl < 2; ++sl) {
            int s = s0 + sl * 2;
            float a = b_gs[n] + b_ls[n];
            #pragma unroll
            for (int q = 0; q < 8; ++q) a += part6[(q*4 + s)*GN + n];
            out[(size_t)(b4 + s) * GN + n] = fmaxf(a, 0.f);
        }
    }
}

extern "C" void kernel_launch(void* const* d_in, const int* in_sizes, int n_in,
                              void* d_out, int out_size, void* d_ws, size_t ws_size,
                              hipStream_t stream) {
    const float* out_state = (const float*)d_in[0];
    const float* img       = (const float*)d_in[1];
    const float* W_loc     = (const float*)d_in[2];
    const float* b_loc     = (const float*)d_in[3];
    const float* W_hg      = (const float*)d_in[4];
    const float* b_hg      = (const float*)d_in[5];
    const float* W_hl      = (const float*)d_in[6];
    const float* b_hl      = (const float*)d_in[7];
    const float* W_gs      = (const float*)d_in[8];
    const float* b_gs      = (const float*)d_in[9];
    const float* W_ls      = (const float*)d_in[10];
    const float* b_ls      = (const float*)d_in[11];
    float* out = (float*)d_out;

    char* ws = (char*)d_ws;
    float* gl_g  = (float*)(ws);                              // 512*768 f32
    float* loc_g = (float*)(ws + (size_t)NB*TSB*4);           // 512*2 f32
    unsigned int* flags = (unsigned int*)(ws + (size_t)NB*TSB*4 + 8192); // 128 u32

    hipLaunchKernelGGL(fused_pair, dim3(NB/2), dim3(512), 0, stream,
                       out_state, img, W_loc, b_loc, W_hg, b_hg,
                       W_hl, b_hl, W_gs, b_gs, W_ls, b_ls,
                       gl_g, loc_g, flags, out);
}

// Round 9
// 16.271 us; speedup vs baseline: 3.0171x; 3.0171x over previous
//
#include <hip/hip_runtime.h>
#include <math.h>

// ---- problem constants ----
#define NB    512   // batch
#define STATE 512
#define IMS   224
#define TSB   768   // 3*16*16
#define HGN   128
#define GN    256
#define WPITCH 65   // 64 + 1 pad
#define NPF   32    // W_hg float4 rows prefetched per thread (of 48)

typedef float f32x4 __attribute__((ext_vector_type(4)));

// depth-1 (32->16) antialiased linear weights: taps at j = 2*o-1 + a
__device__ __forceinline__ void d1w(int o, float w[4]) {
    w[0] = 0.125f; w[1] = 0.375f; w[2] = 0.375f; w[3] = 0.125f;
    if (o == 0)  { w[0] = 0.f;      w[1] = 3.f/7.f; w[2] = 3.f/7.f; w[3] = 1.f/7.f; }
    if (o == 15) { w[0] = 1.f/7.f;  w[1] = 3.f/7.f; w[2] = 3.f/7.f; w[3] = 0.f; }
}
// depth-2 (64->16) weights: taps at j = 4*o-2 + a
__device__ __forceinline__ void d2w(int o, float w[8]) {
    const float s = 1.f/32.f;
    w[0]=1*s; w[1]=3*s; w[2]=5*s; w[3]=7*s; w[4]=7*s; w[5]=5*s; w[6]=3*s; w[7]=1*s;
    if (o == 0)  { const float t=1.f/28.f; w[0]=0.f; w[1]=0.f; w[2]=5*t; w[3]=7*t; w[4]=7*t; w[5]=5*t; w[6]=3*t; w[7]=1*t; }
    if (o == 15) { const float t=1.f/28.f; w[0]=1*t; w[1]=3*t; w[2]=5*t; w[3]=7*t; w[4]=7*t; w[5]=5*t; w[6]=0.f; w[7]=0.f; }
}

#define FMA4(acc, sc, w4) \
    acc.x += (sc) * (w4).x; acc.y += (sc) * (w4).y; \
    acc.z += (sc) * (w4).z; acc.w += (sc) * (w4).w;
#define FMA4V(acc, sc, wv) \
    acc.x += (sc) * (wv)[0]; acc.y += (sc) * (wv)[1]; \
    acc.z += (sc) * (wv)[2]; acc.w += (sc) * (wv)[3];

// Fully fused: loc -> glimpses -> hg -> hl -> g.  2 samples per block, 512 thr.
// R4 structure + T14 async-STAGE: 32/48 W_hg float4 issued via inline-asm
// global_load at the top of phase 3 (pure LDS/VALU), so the L2 weight stream
// overlaps glimpse compute; consumed as pure FMA in phase 4 after an explicit
// vmcnt(0) + sched_barrier(0) (reg-only FMAs may hoist past barriers).
__global__ __launch_bounds__(512) void fused_attn(
    const float* __restrict__ out_state,  // [512][512]
    const float* __restrict__ img,        // [512][224][224]
    const float* __restrict__ W_loc, const float* __restrict__ b_loc,
    const float* __restrict__ W_hg,  const float* __restrict__ b_hg,
    const float* __restrict__ W_hl,  const float* __restrict__ b_hl,
    const float* __restrict__ W_gs,  const float* __restrict__ b_gs,
    const float* __restrict__ W_ls,  const float* __restrict__ b_ls,
    float* __restrict__ out)              // [512][256]
{
    __shared__ float win[2][64 * WPITCH];   // 33.3 KB
    __shared__ float gl[2][TSB];            // 6 KB
    __shared__ float s_hg[2][HGN];
    __shared__ float s_hl[2][HGN];
    __shared__ float part4[2][16][HGN];     // 16 KB
    __shared__ float part6[2][8][GN];       // 16 KB
    __shared__ float red[8][2];
    __shared__ float s_loc[2][2];
    __shared__ int   s_li[2][2];

    const int t  = threadIdx.x;
    const int b0 = blockIdx.x * 2;

    // phase-4 thread mapping (needed for the prefetch addresses)
    const int cg4 = t & 31, q4 = t >> 5;     // 4 cols of 128, 16 k-groups of 48
    const float* wp4 = W_hg + (size_t)(q4 * 48) * HGN + cg4 * 4;

    // ---- phase 1: loc = clip(output @ W_loc + b_loc)
    {
        int s = t >> 8, k = t & 255;
        const float* orow = out_state + (size_t)(b0 + s) * STATE;
        float x0 = orow[k], x1 = orow[k + 256];
        float a0 = x0 * W_loc[k*2]     + x1 * W_loc[(k+256)*2];
        float a1 = x0 * W_loc[k*2 + 1] + x1 * W_loc[(k+256)*2 + 1];
        for (int off = 32; off; off >>= 1) {
            a0 += __shfl_down(a0, off);
            a1 += __shfl_down(a1, off);
        }
        if ((t & 63) == 0) { red[t>>6][0] = a0; red[t>>6][1] = a1; }
    }
    __syncthreads();
    if ((t & 255) == 0) {
        int s = t >> 8;
        float l0 = red[4*s][0]+red[4*s+1][0]+red[4*s+2][0]+red[4*s+3][0] + b_loc[0];
        float l1 = red[4*s][1]+red[4*s+1][1]+red[4*s+2][1]+red[4*s+3][1] + b_loc[1];
        l0 = fminf(fmaxf(l0, -1.f), 1.f);
        l1 = fminf(fmaxf(l1, -1.f), 1.f);
        s_loc[s][0] = l0; s_loc[s][1] = l1;
        s_li[s][0] = (int)rintf((l0 + 1.f) * 0.5f * (float)IMS);
        s_li[s][1] = (int)rintf((l1 + 1.f) * 0.5f * (float)IMS);
    }
    __syncthreads();

    // ---- phase 2: 64x64 windows centered at loc, zero outside image
    #pragma unroll
    for (int i = 0; i < 16; ++i) {
        int idx = t + i * 512;
        int s = idx >> 12, rem = idx & 4095;
        int r = rem >> 6, c = rem & 63;
        int rr = s_li[s][0] - 32 + r, cc = s_li[s][1] - 32 + c;
        float v = 0.f;
        if ((unsigned)rr < (unsigned)IMS && (unsigned)cc < (unsigned)IMS)
            v = img[(size_t)(b0 + s) * IMS * IMS + rr * IMS + cc];
        win[s][r * WPITCH + c] = v;
    }
    __syncthreads();

    // ---- T14 stage-issue: 32 W_hg float4 loads in flight under phase 3
    f32x4 wv[NPF];
    #pragma unroll
    for (int k = 0; k < NPF; ++k) {
        asm volatile("global_load_dwordx4 %0, %1, off"
                     : "=&v"(wv[k])
                     : "v"(wp4 + (size_t)k * HGN));
    }

    // ---- phase 3: 3-depth glimpses -> gl LDS (LDS/VALU only; stream in flight)
    {
        int s = t >> 8, p = t & 255, r = p >> 4, c = p & 15;
        const float* w = win[s];
        gl[s][p] = w[(24 + r) * WPITCH + (24 + c)];
        {
            float wr[4], wc[4];
            d1w(r, wr); d1w(c, wc);
            int jr0 = 16 + 2*r - 1, jc0 = 16 + 2*c - 1;
            float acc = 0.f;
            #pragma unroll
            for (int a = 0; a < 4; ++a) {
                float rowsum = 0.f;
                #pragma unroll
                for (int bb = 0; bb < 4; ++bb)
                    rowsum += wc[bb] * w[(jr0 + a) * WPITCH + (jc0 + bb)];
                acc += wr[a] * rowsum;
            }
            gl[s][256 + p] = acc;
        }
        {
            float wr[8], wc[8];
            d2w(r, wr); d2w(c, wc);
            int jr0 = 4*r - 2, jc0 = 4*c - 2;
            float acc = 0.f;
            #pragma unroll
            for (int a = 0; a < 8; ++a) {
                int jr = min(max(jr0 + a, 0), 63);
                float rowsum = 0.f;
                #pragma unroll
                for (int bb = 0; bb < 8; ++bb) {
                    int jc = min(max(jc0 + bb, 0), 63);
                    rowsum += wc[bb] * w[jr * WPITCH + jc];
                }
                acc += wr[a] * rowsum;
            }
            gl[s][512 + p] = acc;
        }
    }
    __syncthreads();

    // ---- phase 4: hg partials. k<NPF from staged regs, rest from L2.
    {
        // ensure staged loads have landed; block reg-only FMA hoisting (rule #18)
        asm volatile("s_waitcnt vmcnt(0)" ::: "memory");
        __builtin_amdgcn_sched_barrier(0);

        const float* g0 = gl[0] + q4 * 48;
        const float* g1 = gl[1] + q4 * 48;
        float4 acc0 = make_float4(0.f,0.f,0.f,0.f);
        float4 acc1 = acc0;
        #pragma unroll
        for (int k = 0; k < NPF; ++k) {
            float a = g0[k], b = g1[k];
            FMA4V(acc0, a, wv[k]);
            FMA4V(acc1, b, wv[k]);
        }
        #pragma unroll 8
        for (int k = NPF; k < 48; ++k) {
            float4 w4 = *(const float4*)(wp4 + (size_t)k * HGN);
            FMA4(acc0, g0[k], w4);
            FMA4(acc1, g1[k], w4);
        }
        *(float4*)&part4[0][q4][cg4 * 4] = acc0;
        *(float4*)&part4[1][q4][cg4 * 4] = acc1;
    }
    __syncthreads();

    // ---- phase 5: reduce hg partials (t<256) + hl (t>=256)
    {
        int u = t & 255, s = u >> 7, col = u & 127;
        if (t < 256) {
            float a = b_hg[col];
            #pragma unroll
            for (int q = 0; q < 16; ++q) a += part4[s][q][col];
            s_hg[s][col] = fmaxf(a, 0.f);
        } else {
            float l0 = s_loc[s][0], l1 = s_loc[s][1];
            s_hl[s][col] = fmaxf(l0 * W_hl[col] + l1 * W_hl[HGN + col] + b_hl[col], 0.f);
        }
    }
    __syncthreads();

    // ---- phase 6: g partials, weights shared across samples (R4 form)
    {
        int cg = t & 63, q = t >> 6;
        const float* wgs = W_gs + (size_t)(q * 16) * GN + cg * 4;
        const float* wls = W_ls + (size_t)(q * 16) * GN + cg * 4;
        float4 acc0 = make_float4(0.f,0.f,0.f,0.f);
        float4 acc1 = acc0;
        #pragma unroll 8
        for (int j = 0; j < 16; ++j) {
            float4 a4 = *(const float4*)(wgs + (size_t)j * GN);
            float4 b4 = *(const float4*)(wls + (size_t)j * GN);
            int jj = q * 16 + j;
            float hga = s_hg[0][jj], hgb = s_hg[1][jj];
            float hla = s_hl[0][jj], hlb = s_hl[1][jj];
            FMA4(acc0, hga, a4); FMA4(acc0, hla, b4);
            FMA4(acc1, hgb, a4); FMA4(acc1, hlb, b4);
        }
        *(float4*)&part6[0][q][cg * 4] = acc0;
        *(float4*)&part6[1][q][cg * 4] = acc1;
    }
    __syncthreads();
    {
        int s = t >> 8, n = t & 255;
        float a = b_gs[n] + b_ls[n];
        #pragma unroll
        for (int q = 0; q < 8; ++q) a += part6[s][q][n];
        out[(size_t)(b0 + s) * GN + n] = fmaxf(a, 0.f);
    }
}

extern "C" void kernel_launch(void* const* d_in, const int* in_sizes, int n_in,
                              void* d_out, int out_size, void* d_ws, size_t ws_size,
                              hipStream_t stream) {
    const float* out_state = (const float*)d_in[0];
    const float* img       = (const float*)d_in[1];
    const float* W_loc     = (const float*)d_in[2];
    const float* b_loc     = (const float*)d_in[3];
    const float* W_hg      = (const float*)d_in[4];
    const float* b_hg      = (const float*)d_in[5];
    const float* W_hl      = (const float*)d_in[6];
    const float* b_hl      = (const float*)d_in[7];
    const float* W_gs      = (const float*)d_in[8];
    const float* b_gs      = (const float*)d_in[9];
    const float* W_ls      = (const float*)d_in[10];
    const float* b_ls      = (const float*)d_in[11];
    float* out = (float*)d_out;

    hipLaunchKernelGGL(fused_attn, dim3(NB/2), dim3(512), 0, stream,
                       out_state, img, W_loc, b_loc, W_hg, b_hg,
                       W_hl, b_hl, W_gs, b_gs, W_ls, b_ls, out);
}